// Round 1
// baseline (193.990 us; speedup 1.0000x reference)
//
#include <hip/hip_runtime.h>
#include <hip/hip_bf16.h>
#include <stdint.h>

typedef short bf16x8 __attribute__((ext_vector_type(8)));
typedef float f32x4 __attribute__((ext_vector_type(4)));

__device__ __forceinline__ float b2f(unsigned short u) {
    union { unsigned int i; float f; } c; c.i = ((unsigned int)u) << 16; return c.f;
}
__device__ __forceinline__ unsigned short f2b(float f) {
    union { float f; unsigned int i; } c; c.f = f;
    unsigned int u = c.i;
    u += 0x7fffu + ((u >> 16) & 1u);   // round-to-nearest-even
    return (unsigned short)(u >> 16);
}

__device__ __forceinline__ void gload_lds16(const void* g, void* l) {
    __builtin_amdgcn_global_load_lds(
        (const __attribute__((address_space(1))) void*)g,
        (__attribute__((address_space(3))) void*)l, 16, 0, 0);
}

// ---------------- f32 -> bf16 convert (vectorized, grid-stride) ----------------
__global__ __launch_bounds__(256) void f32_to_bf16(const float* __restrict__ in,
                                                   unsigned short* __restrict__ out,
                                                   long n4) {
    long i = (long)blockIdx.x * blockDim.x + threadIdx.x;
    long stride = (long)gridDim.x * blockDim.x;
    for (; i < n4; i += stride) {
        float4 v = ((const float4*)in)[i];
        ushort4 o;
        o.x = f2b(v.x); o.y = f2b(v.y); o.z = f2b(v.z); o.w = f2b(v.w);
        ((ushort4*)out)[i] = o;
    }
}

// ---------------- bf16 transpose: [b][S][D] -> [b][D][S] ----------------
__global__ __launch_bounds__(256) void transpose_bf16(const unsigned short* __restrict__ in,
                                                      unsigned short* __restrict__ out,
                                                      int S, int D) {
    __shared__ unsigned short tile[64][65];
    int d0 = blockIdx.x * 64, s0 = blockIdx.y * 64;
    long base = (long)blockIdx.z * S * D;
    int c = threadIdx.x & 63, rg = threadIdx.x >> 6;  // 4 row groups of 16
    #pragma unroll
    for (int i = 0; i < 16; i++) {
        int r = rg * 16 + i;
        tile[r][c] = in[base + (long)(s0 + r) * D + d0 + c];
    }
    __syncthreads();
    #pragma unroll
    for (int i = 0; i < 16; i++) {
        int r = rg * 16 + i;
        out[base + (long)(d0 + r) * S + s0 + c] = tile[c][r];
    }
}

// ---------------- causal row softmax, in place on bf16 scores ----------------
__global__ __launch_bounds__(256) void softmax_causal(unsigned short* __restrict__ Sb, int S) {
    int rowid = blockIdx.x;
    int b = rowid / S, q = rowid - b * S;
    unsigned short* p = Sb + ((long)b * S + q) * S;
    int t = threadIdx.x, lane = t & 63, wid = t >> 6;
    __shared__ float rmax[4], rsum[4];

    float v[8];
    float mx = -3e38f;
    #pragma unroll
    for (int i = 0; i < 8; i++) {
        int k = i * 256 + t;
        float x = (k <= q) ? b2f(p[k]) : -3e38f;
        v[i] = x; mx = fmaxf(mx, x);
    }
    #pragma unroll
    for (int o = 1; o < 64; o <<= 1) mx = fmaxf(mx, __shfl_xor(mx, o));
    if (lane == 0) rmax[wid] = mx;
    __syncthreads();
    mx = fmaxf(fmaxf(rmax[0], rmax[1]), fmaxf(rmax[2], rmax[3]));

    float s = 0.f;
    #pragma unroll
    for (int i = 0; i < 8; i++) {
        int k = i * 256 + t;
        float e = (k <= q) ? __expf(v[i] - mx) : 0.f;
        v[i] = e; s += e;
    }
    #pragma unroll
    for (int o = 1; o < 64; o <<= 1) s += __shfl_xor(s, o);
    if (lane == 0) rsum[wid] = s;
    __syncthreads();
    s = rsum[0] + rsum[1] + rsum[2] + rsum[3];
    float inv = 1.f / s;
    #pragma unroll
    for (int i = 0; i < 8; i++) {
        p[i * 256 + t] = f2b(v[i] * inv);
    }
}

// ---------------- bf16 GEMM-BT:  C[m][n] = sum_k A[m][k] * B[n][k] ----------------
// MODE 0: QKV projection. C0/C1/C2 = Q/K/V bf16 [8192][1024]; Q scaled by 1/32.
// MODE 1: scores. bf16 out, batched (z), skip upper-triangular blocks.
// MODE 2: PV. f32 out, batched, K_eff = min(K, m0+BM) (causal).
#define BM 128
#define BN 128
#define BK 64

template <int MODE>
__global__ __launch_bounds__(256)
void gemm_bt(const unsigned short* __restrict__ A, const unsigned short* __restrict__ B,
             void* __restrict__ C0, void* __restrict__ C1, void* __restrict__ C2,
             int M, int N, int K,
             long sA, long sB, long sC, int lda, int ldb, int ldc) {
    int mb = blockIdx.y, nb = blockIdx.x, bz = blockIdx.z;
    if (MODE == 1 && nb > mb) return;   // causal block skip

    __shared__ unsigned short As[BM * BK];
    __shared__ unsigned short Bs[BN * BK];

    const unsigned short* Ab = A + (long)bz * sA;
    const unsigned short* Bb = B + (long)bz * sB;

    const int t = threadIdx.x;
    const int lane = t & 63;
    const int wid = t >> 6;
    const int wr = wid >> 1, wc = wid & 1;
    const int m0 = mb * BM, n0 = nb * BN;

    int Keff = K;
    if (MODE == 2) Keff = min(K, m0 + BM);

    f32x4 acc[4][4];
    #pragma unroll
    for (int i = 0; i < 4; i++)
        #pragma unroll
        for (int j = 0; j < 4; j++) acc[i][j] = (f32x4){0.f, 0.f, 0.f, 0.f};

    // staging map: 16B chunk u = i*256+t; row = u>>3; lds chunk = u&7;
    // source chunk = (u&7) ^ (row&7)  (inverse-XOR-swizzled global source, linear LDS dest)
    int rowS[4], csrc[4];
    #pragma unroll
    for (int i = 0; i < 4; i++) {
        int u = i * 256 + t;
        rowS[i] = u >> 3;
        csrc[i] = (u & 7) ^ (rowS[i] & 7);
    }

    for (int k0 = 0; k0 < Keff; k0 += BK) {
        __syncthreads();   // previous compute done before overwrite
        #pragma unroll
        for (int i = 0; i < 4; i++) {
            const unsigned short* gp = Ab + (long)(m0 + rowS[i]) * lda + k0 + csrc[i] * 8;
            gload_lds16(gp, (void*)&As[(i * 256 + wid * 64) * 8]);
        }
        #pragma unroll
        for (int i = 0; i < 4; i++) {
            const unsigned short* gp = Bb + (long)(n0 + rowS[i]) * ldb + k0 + csrc[i] * 8;
            gload_lds16(gp, (void*)&Bs[(i * 256 + wid * 64) * 8]);
        }
        asm volatile("s_waitcnt vmcnt(0)" ::: "memory");
        __syncthreads();

        #pragma unroll
        for (int s = 0; s < 2; s++) {      // two K=32 slices per BK=64
            bf16x8 af[4], bfr[4];
            int kc = s * 4 + (lane >> 4);  // 16B chunk within row
            #pragma unroll
            for (int m = 0; m < 4; m++) {
                int r = wr * 64 + m * 16 + (lane & 15);
                int c = kc ^ (r & 7);
                af[m] = *(const bf16x8*)&As[r * BK + c * 8];
            }
            #pragma unroll
            for (int n = 0; n < 4; n++) {
                int r = wc * 64 + n * 16 + (lane & 15);
                int c = kc ^ (r & 7);
                bfr[n] = *(const bf16x8*)&Bs[r * BK + c * 8];
            }
            #pragma unroll
            for (int m = 0; m < 4; m++)
                #pragma unroll
                for (int n = 0; n < 4; n++)
                    acc[m][n] = __builtin_amdgcn_mfma_f32_16x16x32_bf16(af[m], bfr[n], acc[m][n], 0, 0, 0);
        }
    }

    // epilogue: C/D layout col=lane&15, row=(lane>>4)*4+reg
    const int r0 = (lane >> 4) * 4;
    const int cf = lane & 15;
    if (MODE == 0) {
        int buf = n0 >> 10;  // which of Q/K/V (BN=128 tiles never straddle 1024)
        unsigned short* Cb = (unsigned short*)(buf == 0 ? C0 : (buf == 1 ? C1 : C2));
        float scale = (buf == 0) ? 0.03125f : 1.0f;  // fold 1/sqrt(1024) into Q
        #pragma unroll
        for (int m = 0; m < 4; m++)
            #pragma unroll
            for (int n = 0; n < 4; n++)
                #pragma unroll
                for (int r = 0; r < 4; r++) {
                    long grow = m0 + wr * 64 + m * 16 + r0 + r;
                    int gcol = (n0 & 1023) + wc * 64 + n * 16 + cf;
                    Cb[grow * 1024 + gcol] = f2b(acc[m][n][r] * scale);
                }
    } else if (MODE == 1) {
        unsigned short* Cb = (unsigned short*)C0 + (long)bz * sC;
        #pragma unroll
        for (int m = 0; m < 4; m++)
            #pragma unroll
            for (int n = 0; n < 4; n++)
                #pragma unroll
                for (int r = 0; r < 4; r++) {
                    long grow = m0 + wr * 64 + m * 16 + r0 + r;
                    int gcol = n0 + wc * 64 + n * 16 + cf;
                    Cb[grow * ldc + gcol] = f2b(acc[m][n][r]);
                }
    } else {
        float* Cb = (float*)C0 + (long)bz * sC;
        #pragma unroll
        for (int m = 0; m < 4; m++)
            #pragma unroll
            for (int n = 0; n < 4; n++)
                #pragma unroll
                for (int r = 0; r < 4; r++) {
                    long grow = m0 + wr * 64 + m * 16 + r0 + r;
                    int gcol = n0 + wc * 64 + n * 16 + cf;
                    Cb[grow * ldc + gcol] = acc[m][n][r];
                }
    }
}

extern "C" void kernel_launch(void* const* d_in, const int* in_sizes, int n_in,
                              void* d_out, int out_size, void* d_ws, size_t ws_size,
                              hipStream_t stream) {
    const float* x  = (const float*)d_in[0];
    const float* Wq = (const float*)d_in[1];
    const float* Wk = (const float*)d_in[2];
    const float* Wv = (const float*)d_in[3];

    // B=4, S=2048, D=1024. Workspace layout (bytes):
    char* ws = (char*)d_ws;
    unsigned short* xb = (unsigned short*)(ws);                    // 16 MB  [8192][1024]
    unsigned short* wb = (unsigned short*)(ws + 16777216);         // 6 MB   [3072][1024]
    unsigned short* Qb = (unsigned short*)(ws + 23068672);         // 16 MB  [8192][1024] (pre-scaled)
    unsigned short* Kb = (unsigned short*)(ws + 39845888);         // 16 MB
    unsigned short* Vb = (unsigned short*)(ws + 56623104);         // 16 MB
    unsigned short* Vt = (unsigned short*)(ws + 73400320);         // 16 MB  [b][1024][2048]
    unsigned short* Sb = (unsigned short*)(ws + 90177536);         // 32 MB  [b][2048][2048]

    // 1) convert to bf16
    f32_to_bf16<<<dim3(2048), dim3(256), 0, stream>>>(x, xb, 8388608L / 4);
    f32_to_bf16<<<dim3(256), dim3(256), 0, stream>>>(Wq, wb,           1048576L / 4);
    f32_to_bf16<<<dim3(256), dim3(256), 0, stream>>>(Wk, wb + 1048576, 1048576L / 4);
    f32_to_bf16<<<dim3(256), dim3(256), 0, stream>>>(Wv, wb + 2097152, 1048576L / 4);

    // 2) QKV projection: [8192,1024] x [3072,1024]^T
    gemm_bt<0><<<dim3(24, 64, 1), 256, 0, stream>>>(
        xb, wb, Qb, Kb, Vb, 8192, 3072, 1024, 0L, 0L, 0L, 1024, 1024, 1024);

    // 3) V -> V^T per batch
    transpose_bf16<<<dim3(16, 32, 4), 256, 0, stream>>>(Vb, Vt, 2048, 1024);

    // 4) scores = Qs @ K^T per batch (lower-triangular blocks only)
    gemm_bt<1><<<dim3(16, 16, 4), 256, 0, stream>>>(
        Qb, Kb, Sb, nullptr, nullptr, 2048, 2048, 1024,
        2048L * 1024, 2048L * 1024, 2048L * 2048, 1024, 1024, 2048);

    // 5) causal softmax rows (writes zeros above diagonal)
    softmax_causal<<<dim3(8192), dim3(256), 0, stream>>>(Sb, 2048);

    // 6) O = P @ V  (A=P bf16 [2048,2048], B=Vt [1024,2048], f32 out)
    gemm_bt<2><<<dim3(8, 16, 4), 256, 0, stream>>>(
        Sb, Vt, d_out, nullptr, nullptr, 2048, 1024, 2048,
        2048L * 2048, 1024L * 2048, 2048L * 1024, 2048, 2048, 1024);
}

// Round 3
// 192.354 us; speedup vs baseline: 1.0085x; 1.0085x over previous
//
#include <hip/hip_runtime.h>
#include <hip/hip_bf16.h>
#include <stdint.h>

typedef short bf16x8 __attribute__((ext_vector_type(8)));
typedef float f32x4 __attribute__((ext_vector_type(4)));

__device__ __forceinline__ float b2f(unsigned short u) {
    union { unsigned int i; float f; } c; c.i = ((unsigned int)u) << 16; return c.f;
}
__device__ __forceinline__ unsigned short f2b(float f) {
    union { float f; unsigned int i; } c; c.f = f;
    unsigned int u = c.i;
    u += 0x7fffu + ((u >> 16) & 1u);   // round-to-nearest-even
    return (unsigned short)(u >> 16);
}

__device__ __forceinline__ void gload_lds16(const void* g, void* l) {
    __builtin_amdgcn_global_load_lds(
        (const __attribute__((address_space(1))) void*)g,
        (__attribute__((address_space(3))) void*)l, 16, 0, 0);
}

// ---------------- fused f32 -> bf16 convert: x + Wq + Wk + Wv in one launch ----------------
// unit = one float4. x: 2097152 units -> xb. weights: 3 x 262144 units -> wb (contiguous).
__global__ __launch_bounds__(256) void convert_all(const float* __restrict__ x,
                                                   const float* __restrict__ Wq,
                                                   const float* __restrict__ Wk,
                                                   const float* __restrict__ Wv,
                                                   unsigned short* __restrict__ xb,
                                                   unsigned short* __restrict__ wb) {
    const long X4 = 2097152, W4 = 262144, TOT = X4 + 3 * W4;
    long i = (long)blockIdx.x * blockDim.x + threadIdx.x;
    long stride = (long)gridDim.x * blockDim.x;
    for (; i < TOT; i += stride) {
        const float4* src;
        ushort4* dst;
        if (i < X4) {
            src = (const float4*)x + i;
            dst = (ushort4*)xb + i;
        } else {
            long j = i - X4;
            int w = (int)(j >> 18);          // 262144 = 2^18
            long off = j & (W4 - 1);
            const float* s = (w == 0) ? Wq : (w == 1) ? Wk : Wv;
            src = (const float4*)s + off;
            dst = (ushort4*)wb + (long)w * W4 + off;
        }
        float4 v = *src;
        ushort4 o;
        o.x = f2b(v.x); o.y = f2b(v.y); o.z = f2b(v.z); o.w = f2b(v.w);
        *dst = o;
    }
}

// ---------------- bf16 transpose: [b][S][D] -> [b][D][S], ushort4 global both sides ----------------
__global__ __launch_bounds__(256) void transpose_bf16(const unsigned short* __restrict__ in,
                                                      unsigned short* __restrict__ out,
                                                      int S, int D) {
    __shared__ unsigned short tile[64][65];
    int d0 = blockIdx.x * 64, s0 = blockIdx.y * 64;
    long base = (long)blockIdx.z * S * D;
    int t = threadIdx.x;
    #pragma unroll
    for (int it = 0; it < 4; it++) {
        int u = it * 256 + t;
        int r = u >> 4, c4 = (u & 15) * 4;
        ushort4 v = *(const ushort4*)&in[base + (long)(s0 + r) * D + d0 + c4];
        tile[r][c4 + 0] = v.x; tile[r][c4 + 1] = v.y;
        tile[r][c4 + 2] = v.z; tile[r][c4 + 3] = v.w;
    }
    __syncthreads();
    #pragma unroll
    for (int it = 0; it < 4; it++) {
        int u = it * 256 + t;
        int rr = u >> 4, c4 = (u & 15) * 4;
        ushort4 o;
        o.x = tile[c4 + 0][rr]; o.y = tile[c4 + 1][rr];
        o.z = tile[c4 + 2][rr]; o.w = tile[c4 + 3][rr];
        *(ushort4*)&out[base + (long)(d0 + rr) * S + s0 + c4] = o;
    }
}

// ---------------- causal row softmax, triangular extent, bf16x8 vector I/O ----------------
// Row q only needs cols [0, wl) where wl = (q & ~127) + 128  (PV reads Keff = m0+128 only).
__global__ __launch_bounds__(256) void softmax_causal(unsigned short* __restrict__ Sb, int S) {
    int rowid = blockIdx.x;
    int b = rowid / S, q = rowid - b * S;
    unsigned short* p = Sb + ((long)b * S + q) * S;
    int t = threadIdx.x, lane = t & 63, wid = t >> 6;
    int wl = (q & ~127) + 128;
    int nv = wl >> 3;                       // active vector-threads
    __shared__ float rmax[4], rsum[4];

    float v[8];
    float mx = -3e38f;
    if (t < nv) {
        bf16x8 in8 = *(const bf16x8*)&p[t * 8];
        #pragma unroll
        for (int j = 0; j < 8; j++) {
            int k = t * 8 + j;
            float x = (k <= q) ? b2f((unsigned short)in8[j]) : -3e38f;
            v[j] = x; mx = fmaxf(mx, x);
        }
    } else {
        #pragma unroll
        for (int j = 0; j < 8; j++) v[j] = -3e38f;
    }
    #pragma unroll
    for (int o = 1; o < 64; o <<= 1) mx = fmaxf(mx, __shfl_xor(mx, o));
    if (lane == 0) rmax[wid] = mx;
    __syncthreads();
    mx = fmaxf(fmaxf(rmax[0], rmax[1]), fmaxf(rmax[2], rmax[3]));

    float s = 0.f;
    #pragma unroll
    for (int j = 0; j < 8; j++) {
        int k = t * 8 + j;
        float e = (t < nv && k <= q) ? __expf(v[j] - mx) : 0.f;
        v[j] = e; s += e;
    }
    #pragma unroll
    for (int o = 1; o < 64; o <<= 1) s += __shfl_xor(s, o);
    if (lane == 0) rsum[wid] = s;
    __syncthreads();
    s = rsum[0] + rsum[1] + rsum[2] + rsum[3];
    float inv = 1.f / s;

    if (t < nv) {
        bf16x8 o8;
        #pragma unroll
        for (int j = 0; j < 8; j++) o8[j] = (short)f2b(v[j] * inv);
        *(bf16x8*)&p[t * 8] = o8;
    }
}

// ---------------- bf16 GEMM-BT body:  C[m][n] = sum_k A[m][k] * B[n][k] ----------------
// MODE 0: QKV projection. C0/C1/C2 = Q/K/V bf16; Q scaled by 1/32.
// MODE 1: scores. bf16 out, batched.
// MODE 2: PV. f32 out, batched, K_eff = min(K, m0+BM) (causal).
#define BM 128
#define BN 128
#define BK 64

template <int MODE>
__device__ __forceinline__
void gemm_body(unsigned short* As, unsigned short* Bs,
               const unsigned short* __restrict__ A, const unsigned short* __restrict__ B,
               void* __restrict__ C0, void* __restrict__ C1, void* __restrict__ C2,
               int mb, int nb, int bz, int K,
               long sA, long sB, long sC, int lda, int ldb, int ldc) {
    const unsigned short* Ab = A + (long)bz * sA;
    const unsigned short* Bb = B + (long)bz * sB;

    const int t = threadIdx.x;
    const int lane = t & 63;
    const int wid = t >> 6;
    const int wr = wid >> 1, wc = wid & 1;
    const int m0 = mb * BM, n0 = nb * BN;

    int Keff = K;
    if (MODE == 2) Keff = min(K, m0 + BM);

    f32x4 acc[4][4];
    #pragma unroll
    for (int i = 0; i < 4; i++)
        #pragma unroll
        for (int j = 0; j < 4; j++) acc[i][j] = (f32x4){0.f, 0.f, 0.f, 0.f};

    // staging map: 16B chunk u = i*256+t; row = u>>3; lds chunk = u&7;
    // source chunk = (u&7) ^ (row&7)  (inverse-XOR-swizzled global source, linear LDS dest)
    int rowS[4], csrc[4];
    #pragma unroll
    for (int i = 0; i < 4; i++) {
        int u = i * 256 + t;
        rowS[i] = u >> 3;
        csrc[i] = (u & 7) ^ (rowS[i] & 7);
    }

    for (int k0 = 0; k0 < Keff; k0 += BK) {
        __syncthreads();   // previous compute done before overwrite
        #pragma unroll
        for (int i = 0; i < 4; i++) {
            const unsigned short* gp = Ab + (long)(m0 + rowS[i]) * lda + k0 + csrc[i] * 8;
            gload_lds16(gp, (void*)&As[(i * 256 + wid * 64) * 8]);
        }
        #pragma unroll
        for (int i = 0; i < 4; i++) {
            const unsigned short* gp = Bb + (long)(n0 + rowS[i]) * ldb + k0 + csrc[i] * 8;
            gload_lds16(gp, (void*)&Bs[(i * 256 + wid * 64) * 8]);
        }
        asm volatile("s_waitcnt vmcnt(0)" ::: "memory");
        __syncthreads();

        #pragma unroll
        for (int s = 0; s < 2; s++) {      // two K=32 slices per BK=64
            bf16x8 af[4], bfr[4];
            int kc = s * 4 + (lane >> 4);  // 16B chunk within row
            #pragma unroll
            for (int m = 0; m < 4; m++) {
                int r = wr * 64 + m * 16 + (lane & 15);
                int c = kc ^ (r & 7);
                af[m] = *(const bf16x8*)&As[r * BK + c * 8];
            }
            #pragma unroll
            for (int n = 0; n < 4; n++) {
                int r = wc * 64 + n * 16 + (lane & 15);
                int c = kc ^ (r & 7);
                bfr[n] = *(const bf16x8*)&Bs[r * BK + c * 8];
            }
            #pragma unroll
            for (int m = 0; m < 4; m++)
                #pragma unroll
                for (int n = 0; n < 4; n++)
                    acc[m][n] = __builtin_amdgcn_mfma_f32_16x16x32_bf16(af[m], bfr[n], acc[m][n], 0, 0, 0);
        }
    }

    // epilogue: C/D layout col=lane&15, row=(lane>>4)*4+reg
    const int r0 = (lane >> 4) * 4;
    const int cf = lane & 15;
    if (MODE == 0) {
        int buf = n0 >> 10;  // which of Q/K/V (BN=128 tiles never straddle 1024)
        unsigned short* Cb = (unsigned short*)(buf == 0 ? C0 : (buf == 1 ? C1 : C2));
        float scale = (buf == 0) ? 0.03125f : 1.0f;  // fold 1/sqrt(1024) into Q
        #pragma unroll
        for (int m = 0; m < 4; m++)
            #pragma unroll
            for (int n = 0; n < 4; n++)
                #pragma unroll
                for (int r = 0; r < 4; r++) {
                    long grow = m0 + wr * 64 + m * 16 + r0 + r;
                    int gcol = (n0 & 1023) + wc * 64 + n * 16 + cf;
                    Cb[grow * 1024 + gcol] = f2b(acc[m][n][r] * scale);
                }
    } else if (MODE == 1) {
        unsigned short* Cb = (unsigned short*)C0 + (long)bz * sC;
        #pragma unroll
        for (int m = 0; m < 4; m++)
            #pragma unroll
            for (int n = 0; n < 4; n++)
                #pragma unroll
                for (int r = 0; r < 4; r++) {
                    long grow = m0 + wr * 64 + m * 16 + r0 + r;
                    int gcol = n0 + wc * 64 + n * 16 + cf;
                    Cb[grow * ldc + gcol] = f2b(acc[m][n][r]);
                }
    } else {
        float* Cb = (float*)C0 + (long)bz * sC;
        #pragma unroll
        for (int m = 0; m < 4; m++)
            #pragma unroll
            for (int n = 0; n < 4; n++)
                #pragma unroll
                for (int r = 0; r < 4; r++) {
                    long grow = m0 + wr * 64 + m * 16 + r0 + r;
                    int gcol = n0 + wc * 64 + n * 16 + cf;
                    Cb[grow * ldc + gcol] = acc[m][n][r];
                }
    }
}

// distinct kernel names per stage for unambiguous rocprof rows
__global__ __launch_bounds__(256)
void gemm_qkv(const unsigned short* __restrict__ A, const unsigned short* __restrict__ B,
              void* C0, void* C1, void* C2, int K, int lda, int ldb) {
    __shared__ unsigned short As[BM * BK];
    __shared__ unsigned short Bs[BN * BK];
    gemm_body<0>(As, Bs, A, B, C0, C1, C2, blockIdx.y, blockIdx.x, 0, K,
                 0L, 0L, 0L, lda, ldb, 0);
}

__global__ __launch_bounds__(256)
void gemm_scores(const unsigned short* __restrict__ A, const unsigned short* __restrict__ B,
                 void* C0, int K, long sA, long sB, long sC, int lda, int ldb, int ldc) {
    __shared__ unsigned short As[BM * BK];
    __shared__ unsigned short Bs[BN * BK];
    // compact lower-triangular decode: blockIdx.x in [0,136)
    int l = blockIdx.x;
    int mb = (int)((sqrtf(8.f * l + 1.f) - 1.f) * 0.5f);
    while ((mb + 1) * (mb + 2) / 2 <= l) mb++;
    while (mb * (mb + 1) / 2 > l) mb--;
    int nb = l - mb * (mb + 1) / 2;
    gemm_body<1>(As, Bs, A, B, C0, nullptr, nullptr, mb, nb, blockIdx.z, K,
                 sA, sB, sC, lda, ldb, ldc);
}

__global__ __launch_bounds__(256)
void gemm_pv(const unsigned short* __restrict__ A, const unsigned short* __restrict__ B,
             void* C0, int K, long sA, long sB, long sC, int lda, int ldb, int ldc) {
    __shared__ unsigned short As[BM * BK];
    __shared__ unsigned short Bs[BN * BK];
    int mb = gridDim.y - 1 - blockIdx.y;   // longest (largest Keff) blocks dispatch first
    gemm_body<2>(As, Bs, A, B, C0, nullptr, nullptr, mb, blockIdx.x, blockIdx.z, K,
                 sA, sB, sC, lda, ldb, ldc);
}

extern "C" void kernel_launch(void* const* d_in, const int* in_sizes, int n_in,
                              void* d_out, int out_size, void* d_ws, size_t ws_size,
                              hipStream_t stream) {
    const float* x  = (const float*)d_in[0];
    const float* Wq = (const float*)d_in[1];
    const float* Wk = (const float*)d_in[2];
    const float* Wv = (const float*)d_in[3];

    // B=4, S=2048, D=1024. Workspace layout (bytes):
    char* ws = (char*)d_ws;
    unsigned short* xb = (unsigned short*)(ws);                    // 16 MB  [8192][1024]
    unsigned short* wb = (unsigned short*)(ws + 16777216);         // 6 MB   [3072][1024]
    unsigned short* Qb = (unsigned short*)(ws + 23068672);         // 16 MB  [8192][1024] (pre-scaled)
    unsigned short* Kb = (unsigned short*)(ws + 39845888);         // 16 MB
    unsigned short* Vb = (unsigned short*)(ws + 56623104);         // 16 MB
    unsigned short* Vt = (unsigned short*)(ws + 73400320);         // 16 MB  [b][1024][2048]
    unsigned short* Sb = (unsigned short*)(ws + 90177536);         // 32 MB  [b][2048][2048]

    // 1) convert everything to bf16 in one launch
    convert_all<<<dim3(2048), dim3(256), 0, stream>>>(x, Wq, Wk, Wv, xb, wb);

    // 2) QKV projection: [8192,1024] x [3072,1024]^T
    gemm_qkv<<<dim3(24, 64, 1), 256, 0, stream>>>(xb, wb, Qb, Kb, Vb, 1024, 1024, 1024);

    // 3) V -> V^T per batch
    transpose_bf16<<<dim3(16, 32, 4), 256, 0, stream>>>(Vb, Vt, 2048, 1024);

    // 4) scores = Qs @ K^T per batch (compact lower-triangular grid: 136 blocks)
    gemm_scores<<<dim3(136, 1, 4), 256, 0, stream>>>(
        Qb, Kb, Sb, 1024,
        2048L * 1024, 2048L * 1024, 2048L * 2048, 1024, 1024, 2048);

    // 5) causal softmax rows (triangular extent, vectorized)
    softmax_causal<<<dim3(8192), dim3(256), 0, stream>>>(Sb, 2048);

    // 6) O = P @ V  (A=P bf16 [2048,2048], B=Vt [1024,2048], f32 out)
    // K = 2048 keys (round-2 bug: was 1024, truncated attention for q >= 1024)
    gemm_pv<<<dim3(8, 16, 4), 256, 0, stream>>>(
        Sb, Vt, d_out, 2048,
        2048L * 2048, 1024L * 2048, 2048L * 1024, 2048, 2048, 1024);
}

// Round 4
// 177.601 us; speedup vs baseline: 1.0923x; 1.0831x over previous
//
#include <hip/hip_runtime.h>
#include <hip/hip_bf16.h>
#include <stdint.h>

typedef short bf16x8 __attribute__((ext_vector_type(8)));
typedef float f32x4 __attribute__((ext_vector_type(4)));

__device__ __forceinline__ float b2f(unsigned short u) {
    union { unsigned int i; float f; } c; c.i = ((unsigned int)u) << 16; return c.f;
}
__device__ __forceinline__ unsigned short f2b(float f) {
    union { float f; unsigned int i; } c; c.f = f;
    unsigned int u = c.i;
    u += 0x7fffu + ((u >> 16) & 1u);   // round-to-nearest-even
    return (unsigned short)(u >> 16);
}

__device__ __forceinline__ void gload_lds16(const void* g, void* l) {
    __builtin_amdgcn_global_load_lds(
        (const __attribute__((address_space(1))) void*)g,
        (__attribute__((address_space(3))) void*)l, 16, 0, 0);
}

// ---------------- fused f32 -> bf16 convert: x + Wq + Wk + Wv in one launch ----------------
__global__ __launch_bounds__(256) void convert_all(const float* __restrict__ x,
                                                   const float* __restrict__ Wq,
                                                   const float* __restrict__ Wk,
                                                   const float* __restrict__ Wv,
                                                   unsigned short* __restrict__ xb,
                                                   unsigned short* __restrict__ wb) {
    const long X4 = 2097152, W4 = 262144, TOT = X4 + 3 * W4;
    long i = (long)blockIdx.x * blockDim.x + threadIdx.x;
    long stride = (long)gridDim.x * blockDim.x;
    for (; i < TOT; i += stride) {
        const float4* src;
        ushort4* dst;
        if (i < X4) {
            src = (const float4*)x + i;
            dst = (ushort4*)xb + i;
        } else {
            long j = i - X4;
            int w = (int)(j >> 18);          // 262144 = 2^18
            long off = j & (W4 - 1);
            const float* s = (w == 0) ? Wq : (w == 1) ? Wk : Wv;
            src = (const float4*)s + off;
            dst = (ushort4*)wb + (long)w * W4 + off;
        }
        float4 v = *src;
        ushort4 o;
        o.x = f2b(v.x); o.y = f2b(v.y); o.z = f2b(v.z); o.w = f2b(v.w);
        *dst = o;
    }
}

// ---------------- bf16 transpose: [b][S][D] -> [b][D][S], ushort4 global both sides ----------------
__global__ __launch_bounds__(256) void transpose_bf16(const unsigned short* __restrict__ in,
                                                      unsigned short* __restrict__ out,
                                                      int S, int D) {
    __shared__ unsigned short tile[64][65];
    int d0 = blockIdx.x * 64, s0 = blockIdx.y * 64;
    long base = (long)blockIdx.z * S * D;
    int t = threadIdx.x;
    #pragma unroll
    for (int it = 0; it < 4; it++) {
        int u = it * 256 + t;
        int r = u >> 4, c4 = (u & 15) * 4;
        ushort4 v = *(const ushort4*)&in[base + (long)(s0 + r) * D + d0 + c4];
        tile[r][c4 + 0] = v.x; tile[r][c4 + 1] = v.y;
        tile[r][c4 + 2] = v.z; tile[r][c4 + 3] = v.w;
    }
    __syncthreads();
    #pragma unroll
    for (int it = 0; it < 4; it++) {
        int u = it * 256 + t;
        int rr = u >> 4, c4 = (u & 15) * 4;
        ushort4 o;
        o.x = tile[c4 + 0][rr]; o.y = tile[c4 + 1][rr];
        o.z = tile[c4 + 2][rr]; o.w = tile[c4 + 3][rr];
        *(ushort4*)&out[base + (long)(d0 + rr) * S + s0 + c4] = o;
    }
}

// ---------------- causal row softmax, triangular extent, bf16x8 vector I/O ----------------
// Row q only needs cols [0, wl) where wl = (q & ~127) + 128  (PV reads Keff = m0+128 only).
__global__ __launch_bounds__(256) void softmax_causal(unsigned short* __restrict__ Sb, int S) {
    int rowid = blockIdx.x;
    int b = rowid / S, q = rowid - b * S;
    unsigned short* p = Sb + ((long)b * S + q) * S;
    int t = threadIdx.x, lane = t & 63, wid = t >> 6;
    int wl = (q & ~127) + 128;
    int nv = wl >> 3;                       // active vector-threads
    __shared__ float rmax[4], rsum[4];

    float v[8];
    float mx = -3e38f;
    if (t < nv) {
        bf16x8 in8 = *(const bf16x8*)&p[t * 8];
        #pragma unroll
        for (int j = 0; j < 8; j++) {
            int k = t * 8 + j;
            float x = (k <= q) ? b2f((unsigned short)in8[j]) : -3e38f;
            v[j] = x; mx = fmaxf(mx, x);
        }
    } else {
        #pragma unroll
        for (int j = 0; j < 8; j++) v[j] = -3e38f;
    }
    #pragma unroll
    for (int o = 1; o < 64; o <<= 1) mx = fmaxf(mx, __shfl_xor(mx, o));
    if (lane == 0) rmax[wid] = mx;
    __syncthreads();
    mx = fmaxf(fmaxf(rmax[0], rmax[1]), fmaxf(rmax[2], rmax[3]));

    float s = 0.f;
    #pragma unroll
    for (int j = 0; j < 8; j++) {
        int k = t * 8 + j;
        float e = (t < nv && k <= q) ? __expf(v[j] - mx) : 0.f;
        v[j] = e; s += e;
    }
    #pragma unroll
    for (int o = 1; o < 64; o <<= 1) s += __shfl_xor(s, o);
    if (lane == 0) rsum[wid] = s;
    __syncthreads();
    s = rsum[0] + rsum[1] + rsum[2] + rsum[3];
    float inv = 1.f / s;

    if (t < nv) {
        bf16x8 o8;
        #pragma unroll
        for (int j = 0; j < 8; j++) o8[j] = (short)f2b(v[j] * inv);
        *(bf16x8*)&p[t * 8] = o8;
    }
}

// ---------------- bf16 GEMM-BT:  C[m][n] = sum_k A[m][k] * B[n][k] ----------------
// R1-exact packaging: single __global__ template, __shared__ inside, 14-arg signature.
// MODE 0: QKV projection. C0/C1/C2 = Q/K/V bf16; Q scaled by 1/32.
// MODE 1: scores. bf16 out, batched, compact lower-triangular grid (blockIdx.x in [0,136)).
// MODE 2: PV. f32 out, batched, K_eff = min(K, m0+BM) (causal), longest blocks first.
#define BM 128
#define BN 128
#define BK 64

template <int MODE>
__global__ __launch_bounds__(256)
void gemm_bt(const unsigned short* __restrict__ A, const unsigned short* __restrict__ B,
             void* __restrict__ C0, void* __restrict__ C1, void* __restrict__ C2,
             int M, int N, int K,
             long sA, long sB, long sC, int lda, int ldb, int ldc) {
    int mb, nb;
    if (MODE == 1) {
        // compact lower-triangular decode
        int l = blockIdx.x;
        mb = (int)((sqrtf(8.f * l + 1.f) - 1.f) * 0.5f);
        while ((mb + 1) * (mb + 2) / 2 <= l) mb++;
        while (mb * (mb + 1) / 2 > l) mb--;
        nb = l - mb * (mb + 1) / 2;
    } else if (MODE == 2) {
        mb = gridDim.y - 1 - blockIdx.y;   // largest Keff dispatched first
        nb = blockIdx.x;
    } else {
        mb = blockIdx.y;
        nb = blockIdx.x;
    }
    int bz = blockIdx.z;

    __shared__ unsigned short As[BM * BK];
    __shared__ unsigned short Bs[BN * BK];

    const unsigned short* Ab = A + (long)bz * sA;
    const unsigned short* Bb = B + (long)bz * sB;

    const int t = threadIdx.x;
    const int lane = t & 63;
    const int wid = t >> 6;
    const int wr = wid >> 1, wc = wid & 1;
    const int m0 = mb * BM, n0 = nb * BN;

    int Keff = K;
    if (MODE == 2) Keff = min(K, m0 + BM);

    f32x4 acc[4][4];
    #pragma unroll
    for (int i = 0; i < 4; i++)
        #pragma unroll
        for (int j = 0; j < 4; j++) acc[i][j] = (f32x4){0.f, 0.f, 0.f, 0.f};

    // staging map: 16B chunk u = i*256+t; row = u>>3; lds chunk = u&7;
    // source chunk = (u&7) ^ (row&7)  (inverse-XOR-swizzled global source, linear LDS dest)
    int rowS[4], csrc[4];
    #pragma unroll
    for (int i = 0; i < 4; i++) {
        int u = i * 256 + t;
        rowS[i] = u >> 3;
        csrc[i] = (u & 7) ^ (rowS[i] & 7);
    }

    for (int k0 = 0; k0 < Keff; k0 += BK) {
        __syncthreads();   // previous compute done before overwrite
        #pragma unroll
        for (int i = 0; i < 4; i++) {
            const unsigned short* gp = Ab + (long)(m0 + rowS[i]) * lda + k0 + csrc[i] * 8;
            gload_lds16(gp, (void*)&As[(i * 256 + wid * 64) * 8]);
        }
        #pragma unroll
        for (int i = 0; i < 4; i++) {
            const unsigned short* gp = Bb + (long)(n0 + rowS[i]) * ldb + k0 + csrc[i] * 8;
            gload_lds16(gp, (void*)&Bs[(i * 256 + wid * 64) * 8]);
        }
        asm volatile("s_waitcnt vmcnt(0)" ::: "memory");
        __syncthreads();

        #pragma unroll
        for (int s = 0; s < 2; s++) {      // two K=32 slices per BK=64
            bf16x8 af[4], bfr[4];
            int kc = s * 4 + (lane >> 4);  // 16B chunk within row
            #pragma unroll
            for (int m = 0; m < 4; m++) {
                int r = wr * 64 + m * 16 + (lane & 15);
                int c = kc ^ (r & 7);
                af[m] = *(const bf16x8*)&As[r * BK + c * 8];
            }
            #pragma unroll
            for (int n = 0; n < 4; n++) {
                int r = wc * 64 + n * 16 + (lane & 15);
                int c = kc ^ (r & 7);
                bfr[n] = *(const bf16x8*)&Bs[r * BK + c * 8];
            }
            #pragma unroll
            for (int m = 0; m < 4; m++)
                #pragma unroll
                for (int n = 0; n < 4; n++)
                    acc[m][n] = __builtin_amdgcn_mfma_f32_16x16x32_bf16(af[m], bfr[n], acc[m][n], 0, 0, 0);
        }
    }

    // epilogue: C/D layout col=lane&15, row=(lane>>4)*4+reg
    const int r0 = (lane >> 4) * 4;
    const int cf = lane & 15;
    if (MODE == 0) {
        int buf = n0 >> 10;  // which of Q/K/V (BN=128 tiles never straddle 1024)
        unsigned short* Cb = (unsigned short*)(buf == 0 ? C0 : (buf == 1 ? C1 : C2));
        float scale = (buf == 0) ? 0.03125f : 1.0f;  // fold 1/sqrt(1024) into Q
        #pragma unroll
        for (int m = 0; m < 4; m++)
            #pragma unroll
            for (int n = 0; n < 4; n++)
                #pragma unroll
                for (int r = 0; r < 4; r++) {
                    long grow = m0 + wr * 64 + m * 16 + r0 + r;
                    int gcol = (n0 & 1023) + wc * 64 + n * 16 + cf;
                    Cb[grow * 1024 + gcol] = f2b(acc[m][n][r] * scale);
                }
    } else if (MODE == 1) {
        unsigned short* Cb = (unsigned short*)C0 + (long)bz * sC;
        #pragma unroll
        for (int m = 0; m < 4; m++)
            #pragma unroll
            for (int n = 0; n < 4; n++)
                #pragma unroll
                for (int r = 0; r < 4; r++) {
                    long grow = m0 + wr * 64 + m * 16 + r0 + r;
                    int gcol = n0 + wc * 64 + n * 16 + cf;
                    Cb[grow * ldc + gcol] = f2b(acc[m][n][r]);
                }
    } else {
        float* Cb = (float*)C0 + (long)bz * sC;
        #pragma unroll
        for (int m = 0; m < 4; m++)
            #pragma unroll
            for (int n = 0; n < 4; n++)
                #pragma unroll
                for (int r = 0; r < 4; r++) {
                    long grow = m0 + wr * 64 + m * 16 + r0 + r;
                    int gcol = n0 + wc * 64 + n * 16 + cf;
                    Cb[grow * ldc + gcol] = acc[m][n][r];
                }
    }
}

extern "C" void kernel_launch(void* const* d_in, const int* in_sizes, int n_in,
                              void* d_out, int out_size, void* d_ws, size_t ws_size,
                              hipStream_t stream) {
    const float* x  = (const float*)d_in[0];
    const float* Wq = (const float*)d_in[1];
    const float* Wk = (const float*)d_in[2];
    const float* Wv = (const float*)d_in[3];

    // B=4, S=2048, D=1024. Workspace layout (bytes):
    char* ws = (char*)d_ws;
    unsigned short* xb = (unsigned short*)(ws);                    // 16 MB  [8192][1024]
    unsigned short* wb = (unsigned short*)(ws + 16777216);         // 6 MB   [3072][1024]
    unsigned short* Qb = (unsigned short*)(ws + 23068672);         // 16 MB  [8192][1024] (pre-scaled)
    unsigned short* Kb = (unsigned short*)(ws + 39845888);         // 16 MB
    unsigned short* Vb = (unsigned short*)(ws + 56623104);         // 16 MB
    unsigned short* Vt = (unsigned short*)(ws + 73400320);         // 16 MB  [b][1024][2048]
    unsigned short* Sb = (unsigned short*)(ws + 90177536);         // 32 MB  [b][2048][2048]

    // 1) convert everything to bf16 in one launch
    convert_all<<<dim3(2048), dim3(256), 0, stream>>>(x, Wq, Wk, Wv, xb, wb);

    // 2) QKV projection: [8192,1024] x [3072,1024]^T
    gemm_bt<0><<<dim3(24, 64, 1), 256, 0, stream>>>(
        xb, wb, Qb, Kb, Vb, 8192, 3072, 1024, 0L, 0L, 0L, 1024, 1024, 1024);

    // 3) V -> V^T per batch
    transpose_bf16<<<dim3(16, 32, 4), 256, 0, stream>>>(Vb, Vt, 2048, 1024);

    // 4) scores = Qs @ K^T per batch (compact lower-triangular grid: 136 blocks)
    gemm_bt<1><<<dim3(136, 1, 4), 256, 0, stream>>>(
        Qb, Kb, Sb, nullptr, nullptr, 2048, 2048, 1024,
        2048L * 1024, 2048L * 1024, 2048L * 2048, 1024, 1024, 2048);

    // 5) causal softmax rows (triangular extent, vectorized)
    softmax_causal<<<dim3(8192), dim3(256), 0, stream>>>(Sb, 2048);

    // 6) O = P @ V  (A=P bf16 [2048,2048], B=Vt [1024,2048], f32 out), K = 2048 keys
    gemm_bt<2><<<dim3(8, 16, 4), 256, 0, stream>>>(
        Sb, Vt, d_out, nullptr, nullptr, 2048, 1024, 2048,
        2048L * 2048, 1024L * 2048, 2048L * 1024, 2048, 2048, 1024);
}